// Round 2
// baseline (311.759 us; speedup 1.0000x reference)
//
#include <hip/hip_runtime.h>
#include <stdint.h>
#include <stddef.h>

// MASLoRALinear via concatenation identity:
//   hg[b,t,e*16+r] = SCALING * w[b,e] * (x @ As^T)[b,t,e,r]      (gate baked in)
//   out = [x_bf16 | hg] @ [W_base | Bcat]^T + b_base
// Round 5: main_gemm rewritten as T3+T4 pipelined GEMM: BM=256 BN=128 BK=32,
// 256 thr = 4 waves x (128x64), 2-buffer LDS (48 KB), prefetch distance 1 tile
// with COUNTED vmcnt(6) (never 0 in main loop) -> tile t+1's loads stay in
// flight across both barriers while tile t computes. setprio(1) around MFMA
// cluster. BK=32 row-major LDS is conflict-free for b128 frag reads (no
// swizzle needed). cvt_h/prep_w unchanged from round 4.

#define B_ 16
#define T_ 1500
#define C_ 1024
#define O_ 1024
#define E_ 8
#define R_ 16
#define ER 128     // E*R
#define KK 1152    // C_ + ER
#define BT 24000   // B_*T_  (= 750 * 32 exactly)
#define NT 36      // KK / 32 K-steps
#define SCALING 2.0f

typedef __bf16 bf16x8 __attribute__((ext_vector_type(8)));
typedef float f32x4 __attribute__((ext_vector_type(4)));
typedef unsigned short u16;

__device__ inline u16 f2bf(float f) {
  union { float f; unsigned u; } v; v.f = f;
  unsigned u = v.u;
  u += 0x7fff + ((u >> 16) & 1);  // RNE
  return (u16)(u >> 16);
}

#define GLL(gp, lp)                                                            \
  __builtin_amdgcn_global_load_lds(                                            \
      (const __attribute__((address_space(1))) void*)(gp),                     \
      (__attribute__((address_space(3))) void*)(lp), 16, 0, 0)

// ---------------- kernel 1: prep weights ----------------
// wp[o][0:1024]=bf16(W_base), wp[o][1024+e*16+r]=bf16(Bs[e,o,r]); ap=bf16(As flat).
__global__ __launch_bounds__(256) void prep_w(const float* __restrict__ Wb,
                                              const float* __restrict__ Bs,
                                              const float* __restrict__ As,
                                              u16* __restrict__ wp,
                                              u16* __restrict__ ap) {
  int idx = blockIdx.x * 256 + threadIdx.x;
  if (idx < O_ * KK) {
    int o = idx / KK;
    int k = idx - o * KK;
    float v;
    if (k < C_) {
      v = Wb[o * C_ + k];
    } else {
      int j = k - C_;
      v = Bs[((j >> 4) * O_ + o) * R_ + (j & 15)];
    }
    wp[idx] = f2bf(v);
  } else {
    int a = idx - O_ * KK;  // 131,072 elements of As
    ap[a] = f2bf(As[a]);
  }
}

// ---------------- kernel 2: fused convert + h-GEMM + gate ----------------
// Per 32-row M-tile (750 blocks): stream x fp32, convert to bf16 in regs,
// ds_write into pad-72 LDS A AND store to X'[:,0:1024]; MFMA vs Asb staged via
// GLL at BK=64 (8-chunk XOR swizzle); epilogue writes gated hg into
// X'[:,1024:1152]. Waves 2x2: each 16 rows x 64 cols (acc[4]).
__global__ __launch_bounds__(256) void cvt_h(const float* __restrict__ x,
                                             const u16* __restrict__ ab,
                                             const float* __restrict__ w,
                                             u16* __restrict__ xp) {
  const int mt = blockIdx.x;  // 0..749 (exact: 750*32 = 24000)
  const int tid = threadIdx.x, lane = tid & 63, wv = tid >> 6;
  const int wrow = wv & 1, wcol = wv >> 1, l15 = lane & 15, quad = lane >> 4;
  const int s7 = l15 & 7;

  __shared__ u16 lA[32 * 72];   // row stride 72 u16 = 144 B
  __shared__ u16 lB[128 * 64];  // GLL-staged, 8-chunk XOR swizzle

  const size_t row0 = (size_t)mt * 32;

  f32x4 acc[4];
#pragma unroll
  for (int j = 0; j < 4; ++j) acc[j] = (f32x4){0.f, 0.f, 0.f, 0.f};

  int brow[4], bko[4];
#pragma unroll
  for (int c = 0; c < 4; ++c) {
    int idx = c * 256 + tid;
    brow[c] = idx >> 3;
    bko[c] = (((idx & 7) ^ (brow[c] & 7)) << 3);
  }

  const int xr = tid >> 3;             // 0..31
  const int xc = (tid & 7) * 4;        // 0,4,..,28  (two col-halves: +0, +32)

  for (int kt = 0; kt < C_ / 64; ++kt) {  // 16 iterations
    const int k0 = kt * 64;
#pragma unroll
    for (int c = 0; c < 4; ++c)
      GLL(ab + brow[c] * C_ + k0 + bko[c], &lB[(c * 256 + tid) * 8]);
    float4 v0 = *(const float4*)&x[(row0 + xr) * C_ + k0 + xc];
    float4 v1 = *(const float4*)&x[(row0 + xr) * C_ + k0 + 32 + xc];
    ushort4 o0, o1;
    o0.x = f2bf(v0.x); o0.y = f2bf(v0.y); o0.z = f2bf(v0.z); o0.w = f2bf(v0.w);
    o1.x = f2bf(v1.x); o1.y = f2bf(v1.y); o1.z = f2bf(v1.z); o1.w = f2bf(v1.w);
    *(ushort4*)&lA[xr * 72 + xc] = o0;
    *(ushort4*)&lA[xr * 72 + 32 + xc] = o1;
    *(ushort4*)&xp[(row0 + xr) * KK + k0 + xc] = o0;
    *(ushort4*)&xp[(row0 + xr) * KK + k0 + 32 + xc] = o1;
    __syncthreads();  // drains GLL (vmcnt) + ds_writes (lgkmcnt)
#pragma unroll
    for (int kk = 0; kk < 2; ++kk) {
      bf16x8 af = *(const bf16x8*)&lA[(wrow * 16 + l15) * 72 + kk * 32 + quad * 8];
      bf16x8 bfr[4];
#pragma unroll
      for (int j = 0; j < 4; ++j)
        bfr[j] = *(const bf16x8*)&lB[(wcol * 64 + j * 16 + l15) * 64 +
                                     (((kk * 4 + quad) ^ s7) << 3)];
#pragma unroll
      for (int j = 0; j < 4; ++j)
        acc[j] = __builtin_amdgcn_mfma_f32_16x16x32_bf16(af, bfr[j], acc[j], 0, 0, 0);
    }
    __syncthreads();
  }

  // epilogue: col -> expert e = wcol*4+j (lane-uniform), rank r = l15
#pragma unroll
  for (int j = 0; j < 4; ++j) {
    const int col = wcol * 64 + j * 16 + l15;
    const int e = wcol * 4 + j;
#pragma unroll
    for (int rr = 0; rr < 4; ++rr) {
      const int row = mt * 32 + wrow * 16 + quad * 4 + rr;
      const int b = row / T_;
      xp[(size_t)row * KK + C_ + col] = f2bf(acc[j][rr] * (SCALING * w[b * E_ + e]));
    }
  }
}

// ---------------- kernel 3: main GEMM (T3+T4 pipelined) ----------------
// out[row][o] = X'[row,:] . W'[o,:] + b_base[o];  M=24000 K=1152 N=1024.
// BM=256 BN=128 BK=32; 256 thr = 4 waves (2M x 2N), each wave 128x64 out
// (acc[8][4], 12 ds_read_b128 -> 32 MFMA per K-step). 2-buffer LDS: while
// computing tile t from buf[t&1], tile t+1's 6 GLLs fly; iteration start
// waits only vmcnt(6) (counted, not 0). Per iter:
//   lgkmcnt(0); barrier; stage t+1; vmcnt(6); barrier; ds_read+MFMA.
// Barrier #1 makes stage-into-buf[(t+1)&1] safe (last read was iter t-1,
// lgkm drained); barrier #2 publishes tile t's landed LDS to all waves.
// XCD-affine map: 8 consecutive same-XCD ids share mt, sweep nt=0..7.
__global__ __launch_bounds__(256, 2) void main_gemm(const u16* __restrict__ xp,
                                                    const u16* __restrict__ wp,
                                                    const float* __restrict__ bb,
                                                    float* __restrict__ out) {
  const int id = blockIdx.x;                     // 0..767
  const int mt = ((id >> 6) << 3) | (id & 7);    // 0..95
  const int nt = (id >> 3) & 7;                  // 0..7
  if (mt >= 94) return;                          // uniform early-exit (before barriers)
  const int tid = threadIdx.x, lane = tid & 63, wv = tid >> 6;  // 4 waves
  const int wm = wv >> 1, wn = wv & 1, l15 = lane & 15, quad = lane >> 4;

  __shared__ u16 lA[2][256 * 32];  // 2 x 16 KB
  __shared__ u16 lB[2][128 * 32];  // 2 x  8 KB

  const u16* gA = xp + (size_t)mt * 256 * KK;
  const u16* gB = wp + (size_t)nt * 128 * KK;

  f32x4 acc[8][4];
#pragma unroll
  for (int i = 0; i < 8; ++i)
#pragma unroll
    for (int j = 0; j < 4; ++j) acc[i][j] = (f32x4){0.f, 0.f, 0.f, 0.f};

  // staging: A = 4 GLL rounds (1024 chunks), B = 2 rounds (512 chunks); linear.
  const u16* pa[4];
  const u16* pb[2];
  int dA[4], dB[2];
#pragma unroll
  for (int c = 0; c < 4; ++c) {
    int idx = c * 256 + tid;            // 0..1023: row=idx>>2 (0..255), chunk=idx&3
    pa[c] = gA + (size_t)(idx >> 2) * KK + (idx & 3) * 8;
    dA[c] = idx * 8;
  }
#pragma unroll
  for (int c = 0; c < 2; ++c) {
    int idx = c * 256 + tid;            // 0..511: row=idx>>2 (0..127), chunk=idx&3
    pb[c] = gB + (size_t)(idx >> 2) * KK + (idx & 3) * 8;
    dB[c] = idx * 8;
  }

  // frag read offsets (u16 units), constant per thread
  const int offA = (wm * 128 + l15) * 32 + quad * 8;  // + i*512
  const int offB = (wn * 64 + l15) * 32 + quad * 8;   // + j*512

  // prologue: stage tile 0 into buf0
#pragma unroll
  for (int c = 0; c < 4; ++c) { GLL(pa[c], &lA[0][dA[c]]); pa[c] += 32; }
#pragma unroll
  for (int c = 0; c < 2; ++c) { GLL(pb[c], &lB[0][dB[c]]); pb[c] += 32; }

  for (int t = 0; t < NT; ++t) {
    const int cur = t & 1, nxt = cur ^ 1;
    asm volatile("s_waitcnt lgkmcnt(0)" ::: "memory");
    __builtin_amdgcn_sched_barrier(0);
    __builtin_amdgcn_s_barrier();          // barrier #1: prev reads of buf[nxt] done
    __builtin_amdgcn_sched_barrier(0);
    if (t + 1 < NT) {
#pragma unroll
      for (int c = 0; c < 4; ++c) { GLL(pa[c], &lA[nxt][dA[c]]); pa[c] += 32; }
#pragma unroll
      for (int c = 0; c < 2; ++c) { GLL(pb[c], &lB[nxt][dB[c]]); pb[c] += 32; }
      asm volatile("s_waitcnt vmcnt(6)" ::: "memory");   // tile t landed; t+1 flying
    } else {
      asm volatile("s_waitcnt vmcnt(0)" ::: "memory");   // tail: drain last tile
    }
    __builtin_amdgcn_sched_barrier(0);
    __builtin_amdgcn_s_barrier();          // barrier #2: tile t visible to all waves
    __builtin_amdgcn_sched_barrier(0);

    bf16x8 af[8], bfr[4];
#pragma unroll
    for (int i = 0; i < 8; ++i)
      af[i] = *(const bf16x8*)&lA[cur][offA + i * 512];
#pragma unroll
    for (int j = 0; j < 4; ++j)
      bfr[j] = *(const bf16x8*)&lB[cur][offB + j * 512];
    __builtin_amdgcn_s_setprio(1);
#pragma unroll
    for (int i = 0; i < 8; ++i)
#pragma unroll
      for (int j = 0; j < 4; ++j)
        acc[i][j] = __builtin_amdgcn_mfma_f32_16x16x32_bf16(af[i], bfr[j], acc[i][j], 0, 0, 0);
    __builtin_amdgcn_s_setprio(0);
  }

#pragma unroll
  for (int j = 0; j < 4; ++j) {
    const int col = nt * 128 + wn * 64 + j * 16 + l15;
    const float bias = bb[col];
#pragma unroll
    for (int i = 0; i < 8; ++i) {
#pragma unroll
      for (int rr = 0; rr < 4; ++rr) {
        const int row = mt * 256 + wm * 128 + i * 16 + quad * 4 + rr;
        if (row < BT) out[(size_t)row * O_ + col] = acc[i][j][rr] + bias;
      }
    }
  }
}

extern "C" void kernel_launch(void* const* d_in, const int* in_sizes, int n_in,
                              void* d_out, int out_size, void* d_ws, size_t ws_size,
                              hipStream_t stream) {
  const float* x = (const float*)d_in[0];    // (16,1500,1024)
  const float* w = (const float*)d_in[1];    // (16,8)
  const float* Wb = (const float*)d_in[2];   // (1024,1024)
  const float* bb = (const float*)d_in[3];   // (1024,)
  const float* As = (const float*)d_in[4];   // (8,16,1024)
  const float* Bs = (const float*)d_in[5];   // (8,1024,16)
  float* out = (float*)d_out;                // (16,1500,1024) fp32

  // ws: X' (24000x1152 u16, 55.30 MB) | W' (1024x1152 u16, 2.36 MB) | Asb (128x1024 u16, 0.26 MB)
  // main_gemm mt=93 staging over-reads rows 24000..24063 -> land in W' region (allocated, masked).
  u16* xp = (u16*)d_ws;
  u16* wp = xp + (size_t)BT * KK;
  u16* ap = wp + (size_t)O_ * KK;

  prep_w<<<(O_ * KK + ER * C_) / 256, 256, 0, stream>>>(Wb, Bs, As, wp, ap);
  cvt_h<<<750, 256, 0, stream>>>(x, ap, w, xp);
  main_gemm<<<768, 256, 0, stream>>>(xp, wp, bb, out);
}

// Round 3
// 292.369 us; speedup vs baseline: 1.0663x; 1.0663x over previous
//
#include <hip/hip_runtime.h>
#include <stdint.h>
#include <stddef.h>

// MASLoRALinear via concatenation identity:
//   hg[b,t,e*16+r] = SCALING * w[b,e] * (x @ As^T)[b,t,e,r]      (gate baked in)
//   out = [x_bf16 | hg] @ [W_base | Bcat]^T + b_base
// Round 6: the fused cvt_h (measured ~180 us: HBM x-loads + converts inside a
// barrier-drained MFMA loop) is split into (a) cvt: pure streaming fp32->bf16
// convert (no barriers, memory-roofline) and (b) h_gemm: bf16 LoRA GEMM
// M=24000 N=128 K=1024 reading x back as bf16 (47 MB not 98), round-1-verified
// conflict-free BK=64 XOR-8 structure, 375 blocks. main_gemm reverted verbatim
// to the round-0 version (best measured: 94.2 us).

#define B_ 16
#define T_ 1500
#define C_ 1024
#define O_ 1024
#define E_ 8
#define R_ 16
#define ER 128     // E*R
#define KK 1152    // C_ + ER
#define BT 24000   // B_*T_
#define SCALING 2.0f

typedef __bf16 bf16x8 __attribute__((ext_vector_type(8)));
typedef float f32x4 __attribute__((ext_vector_type(4)));
typedef unsigned short u16;
typedef u16 u16x8 __attribute__((ext_vector_type(8)));

__device__ inline u16 f2bf(float f) {
  union { float f; unsigned u; } v; v.f = f;
  unsigned u = v.u;
  u += 0x7fff + ((u >> 16) & 1);  // RNE
  return (u16)(u >> 16);
}

#define GLL(gp, lp)                                                            \
  __builtin_amdgcn_global_load_lds(                                            \
      (const __attribute__((address_space(1))) void*)(gp),                     \
      (__attribute__((address_space(3))) void*)(lp), 16, 0, 0)

// ---------------- kernel 1: prep weights ----------------
// wp[o][0:1024]=bf16(W_base), wp[o][1024+e*16+r]=bf16(Bs[e,o,r]); ap=bf16(As flat).
__global__ __launch_bounds__(256) void prep_w(const float* __restrict__ Wb,
                                              const float* __restrict__ Bs,
                                              const float* __restrict__ As,
                                              u16* __restrict__ wp,
                                              u16* __restrict__ ap) {
  int idx = blockIdx.x * 256 + threadIdx.x;
  if (idx < O_ * KK) {
    int o = idx / KK;
    int k = idx - o * KK;
    float v;
    if (k < C_) {
      v = Wb[o * C_ + k];
    } else {
      int j = k - C_;
      v = Bs[((j >> 4) * O_ + o) * R_ + (j & 15)];
    }
    wp[idx] = f2bf(v);
  } else {
    int a = idx - O_ * KK;  // 131,072 elements of As
    ap[a] = f2bf(As[a]);
  }
}

// ---------------- kernel 2a: streaming convert ----------------
// x fp32 (24000x1024) -> xp bf16 cols 0:1024 (row stride 1152). Pure
// memory-roofline: 98 MB read + 47 MB write, no barriers, no LDS.
// 2000 blocks x 256 thr x 6 chunks x 8 elems = 24,576,000 elems exactly.
__global__ __launch_bounds__(256) void cvt(const float* __restrict__ x,
                                           u16* __restrict__ xp) {
  const int t0 = blockIdx.x * 256 + threadIdx.x;  // 0..511999
#pragma unroll
  for (int u = 0; u < 6; ++u) {
    const int chunk = u * 512000 + t0;            // 0..3,071,999
    const int row = chunk >> 7;                   // 0..23999
    const int cc = (chunk & 127) * 8;             // 0..1016
    const float4 v0 = *(const float4*)&x[(size_t)row * C_ + cc];
    const float4 v1 = *(const float4*)&x[(size_t)row * C_ + cc + 4];
    u16x8 o;
    o[0] = f2bf(v0.x); o[1] = f2bf(v0.y); o[2] = f2bf(v0.z); o[3] = f2bf(v0.w);
    o[4] = f2bf(v1.x); o[5] = f2bf(v1.y); o[6] = f2bf(v1.z); o[7] = f2bf(v1.w);
    *(u16x8*)&xp[(size_t)row * KK + cc] = o;
  }
}

// ---------------- kernel 2b: LoRA h-GEMM + gate ----------------
// hg[row, e*16+r] = SCALING * w[b,e] * (x_bf16 @ As^T)  -> xp cols 1024:1152.
// M=24000 (375 x 64-row tiles), N=128, K=1024, BK=64. Same conflict-free
// XOR-8 staging/read addressing as the round-1 main_gemm (0 bank conflicts
// verified). lB = entire As k-slice (128x64), L2-resident source (256 KB).
// Waves 2x2: each 32 rows x 64 cols (acc[2][4]).
__global__ __launch_bounds__(256) void h_gemm(const u16* __restrict__ xp,
                                              const u16* __restrict__ ab,
                                              const float* __restrict__ w,
                                              u16* __restrict__ xpo) {
  const int mt = blockIdx.x;  // 0..374 (exact: 375*64 = 24000)
  const int tid = threadIdx.x, lane = tid & 63, wv = tid >> 6;
  const int wrow = wv & 1, wcol = wv >> 1, l15 = lane & 15, quad = lane >> 4;
  const int s7 = l15 & 7;

  __shared__ u16 lA[64 * 64];    // 8 KB
  __shared__ u16 lB[128 * 64];   // 16 KB

  const u16* gA = xp + (size_t)mt * 64 * KK;

  f32x4 acc[2][4];
#pragma unroll
  for (int i = 0; i < 2; ++i)
#pragma unroll
    for (int j = 0; j < 4; ++j) acc[i][j] = (f32x4){0.f, 0.f, 0.f, 0.f};

  // staging: 8-chunk XOR swizzle; phys chunk p of row r holds logical p^(r&7)
  int arow[2], ako[2], brow[4], bko[4];
#pragma unroll
  for (int c = 0; c < 2; ++c) {
    int idx = c * 256 + tid;            // 0..511: row=idx>>3 (0..63)
    arow[c] = idx >> 3;
    ako[c] = (((idx & 7) ^ (arow[c] & 7)) << 3);
  }
#pragma unroll
  for (int c = 0; c < 4; ++c) {
    int idx = c * 256 + tid;            // 0..1023: row=idx>>3 (0..127)
    brow[c] = idx >> 3;
    bko[c] = (((idx & 7) ^ (brow[c] & 7)) << 3);
  }

  for (int kt = 0; kt < C_ / 64; ++kt) {  // 16 iterations
    const int k0 = kt * 64;
#pragma unroll
    for (int c = 0; c < 2; ++c)
      GLL(gA + (size_t)arow[c] * KK + k0 + ako[c], &lA[(c * 256 + tid) * 8]);
#pragma unroll
    for (int c = 0; c < 4; ++c)
      GLL(ab + brow[c] * C_ + k0 + bko[c], &lB[(c * 256 + tid) * 8]);
    __syncthreads();
#pragma unroll
    for (int kk = 0; kk < 2; ++kk) {
      const int ko = (((kk * 4 + quad) ^ s7) << 3);
      bf16x8 af[2], bfr[4];
#pragma unroll
      for (int i = 0; i < 2; ++i)
        af[i] = *(const bf16x8*)&lA[(wrow * 32 + i * 16 + l15) * 64 + ko];
#pragma unroll
      for (int j = 0; j < 4; ++j)
        bfr[j] = *(const bf16x8*)&lB[(wcol * 64 + j * 16 + l15) * 64 + ko];
#pragma unroll
      for (int i = 0; i < 2; ++i)
#pragma unroll
        for (int j = 0; j < 4; ++j)
          acc[i][j] = __builtin_amdgcn_mfma_f32_16x16x32_bf16(af[i], bfr[j], acc[i][j], 0, 0, 0);
    }
    __syncthreads();
  }

  // epilogue: col -> expert e = wcol*4+j (lane-uniform), rank r = l15
#pragma unroll
  for (int j = 0; j < 4; ++j) {
    const int col = wcol * 64 + j * 16 + l15;
    const int e = wcol * 4 + j;
#pragma unroll
    for (int i = 0; i < 2; ++i) {
#pragma unroll
      for (int rr = 0; rr < 4; ++rr) {
        const int row = mt * 64 + wrow * 32 + i * 16 + quad * 4 + rr;
        const int b = row / T_;
        xpo[(size_t)row * KK + C_ + col] = f2bf(acc[i][j][rr] * (SCALING * w[b * E_ + e]));
      }
    }
  }
}

// ---------------- kernel 3: main GEMM (round-0 verbatim) ----------------
// out[row][o] = X'[row,:] . W'[o,:] + b_base[o];  M=24000 K=1152 N=1024.
// XCD-affine map: all 8 nt's of one mt share id%8 (same XCD, adjacent launch)
// -> A-tile fetched once per XCD; W' (2.3 MB) L2-resident per XCD.
__global__ __launch_bounds__(256) void main_gemm(const u16* __restrict__ xp,
                                                 const u16* __restrict__ wp,
                                                 const float* __restrict__ bb,
                                                 float* __restrict__ out) {
  const int id = blockIdx.x;                     // 0..1535
  const int mt = ((id >> 6) << 3) | (id & 7);    // 0..191
  const int nt = (id >> 3) & 7;                  // 0..7
  if (mt >= 188) return;                          // uniform early-exit (no barriers yet)
  const int tid = threadIdx.x, lane = tid & 63, wv = tid >> 6;
  const int wrow = wv & 1, wcol = wv >> 1, l15 = lane & 15, quad = lane >> 4;
  const int kx = quad ^ (l15 & 3) ^ ((l15 >> 2) & 3);

  __shared__ u16 lA[128 * 32];
  __shared__ u16 lB[128 * 32];
  const u16* gA = xp + (size_t)mt * 128 * KK;
  const u16* gB = wp + (size_t)nt * 128 * KK;

  f32x4 acc[4][4];
#pragma unroll
  for (int i = 0; i < 4; ++i)
#pragma unroll
    for (int j = 0; j < 4; ++j) acc[i][j] = (f32x4){0.f, 0.f, 0.f, 0.f};

  const int idx0 = tid, idx1 = 256 + tid;
  const int r0 = idx0 >> 2, kc0 = (idx0 & 3) ^ (r0 & 3) ^ ((r0 >> 2) & 3);
  const int r1 = idx1 >> 2, kc1 = (idx1 & 3) ^ (r1 & 3) ^ ((r1 >> 2) & 3);

  for (int kt = 0; kt < KK / 32; ++kt) {  // 36 iterations
    const int k0 = kt * 32;
    GLL(gA + (size_t)r0 * KK + k0 + kc0 * 8, &lA[idx0 * 8]);
    GLL(gA + (size_t)r1 * KK + k0 + kc1 * 8, &lA[idx1 * 8]);
    GLL(gB + (size_t)r0 * KK + k0 + kc0 * 8, &lB[idx0 * 8]);
    GLL(gB + (size_t)r1 * KK + k0 + kc1 * 8, &lB[idx1 * 8]);
    __syncthreads();
    bf16x8 af[4], bfr[4];
#pragma unroll
    for (int i = 0; i < 4; ++i) {
      af[i] = *(const bf16x8*)&lA[(wrow * 64 + i * 16 + l15) * 32 + kx * 8];
      bfr[i] = *(const bf16x8*)&lB[(wcol * 64 + i * 16 + l15) * 32 + kx * 8];
    }
#pragma unroll
    for (int i = 0; i < 4; ++i)
#pragma unroll
      for (int j = 0; j < 4; ++j)
        acc[i][j] = __builtin_amdgcn_mfma_f32_16x16x32_bf16(af[i], bfr[j], acc[i][j], 0, 0, 0);
    __syncthreads();
  }

#pragma unroll
  for (int j = 0; j < 4; ++j) {
    const int col = nt * 128 + wcol * 64 + j * 16 + l15;
    const float bias = bb[col];
#pragma unroll
    for (int i = 0; i < 4; ++i) {
#pragma unroll
      for (int rr = 0; rr < 4; ++rr) {
        const int row = mt * 128 + wrow * 64 + i * 16 + quad * 4 + rr;
        if (row < BT) out[(size_t)row * O_ + col] = acc[i][j][rr] + bias;
      }
    }
  }
}

extern "C" void kernel_launch(void* const* d_in, const int* in_sizes, int n_in,
                              void* d_out, int out_size, void* d_ws, size_t ws_size,
                              hipStream_t stream) {
  const float* x = (const float*)d_in[0];    // (16,1500,1024)
  const float* w = (const float*)d_in[1];    // (16,8)
  const float* Wb = (const float*)d_in[2];   // (1024,1024)
  const float* bb = (const float*)d_in[3];   // (1024,)
  const float* As = (const float*)d_in[4];   // (8,16,1024)
  const float* Bs = (const float*)d_in[5];   // (8,1024,16)
  float* out = (float*)d_out;                // (16,1500,1024) fp32

  // ws: X' (24000x1152 u16, 55.30 MB) | W' (1024x1152 u16, 2.36 MB) | Asb (128x1024 u16, 0.26 MB)
  // main_gemm mt=187 staging over-reads rows 24000..24063 -> land in W' region (allocated, masked).
  u16* xp = (u16*)d_ws;
  u16* wp = xp + (size_t)BT * KK;
  u16* ap = wp + (size_t)O_ * KK;

  prep_w<<<(O_ * KK + ER * C_) / 256, 256, 0, stream>>>(Wb, Bs, As, wp, ap);
  cvt<<<2000, 256, 0, stream>>>(x, xp);
  h_gemm<<<375, 256, 0, stream>>>(xp, ap, w, xp);
  main_gemm<<<1536, 256, 0, stream>>>(xp, wp, bb, out);
}

// Round 5
// 290.385 us; speedup vs baseline: 1.0736x; 1.0068x over previous
//
#include <hip/hip_runtime.h>
#include <stdint.h>
#include <stddef.h>

// MASLoRALinear via concatenation identity:
//   hg[b,t,e*16+r] = SCALING * w[b,e] * (x @ As^T)[b,t,e,r]      (gate baked in)
//   out = [x_bf16 | hg] @ [W_base | Bcat]^T + b_base
// Round 8: RESUBMISSION of round 7 (bench infra failed twice; kernel audited
// for deadlock/hang mechanisms -- none found: uniform barriers over 1504 full
// tiles, monotone vmcnt waits, legal GLL lane-contiguous destinations).
// main_gemm: counted-vmcnt double-buffered pipeline, BK=64, XOR-8
// conflict-free LDS addressing, LDS 64 KB -> 2 blocks/CU, prefetch distance
// 1 K-tile (vmcnt(8) in main loop, never 0), t+2 staging issued before the
// MFMA cluster. cvt/h_gemm/prep_w unchanged.

#define B_ 16
#define T_ 1500
#define C_ 1024
#define O_ 1024
#define E_ 8
#define R_ 16
#define ER 128     // E*R
#define KK 1152    // C_ + ER
#define BT 24000   // B_*T_
#define NKT 18     // KK / 64 K-tiles
#define SCALING 2.0f

typedef __bf16 bf16x8 __attribute__((ext_vector_type(8)));
typedef float f32x4 __attribute__((ext_vector_type(4)));
typedef unsigned short u16;
typedef u16 u16x8 __attribute__((ext_vector_type(8)));

__device__ inline u16 f2bf(float f) {
  union { float f; unsigned u; } v; v.f = f;
  unsigned u = v.u;
  u += 0x7fff + ((u >> 16) & 1);  // RNE
  return (u16)(u >> 16);
}

#define GLL(gp, lp)                                                            \
  __builtin_amdgcn_global_load_lds(                                            \
      (const __attribute__((address_space(1))) void*)(gp),                     \
      (__attribute__((address_space(3))) void*)(lp), 16, 0, 0)

// ---------------- kernel 1: prep weights ----------------
// wp[o][0:1024]=bf16(W_base), wp[o][1024+e*16+r]=bf16(Bs[e,o,r]); ap=bf16(As flat).
__global__ __launch_bounds__(256) void prep_w(const float* __restrict__ Wb,
                                              const float* __restrict__ Bs,
                                              const float* __restrict__ As,
                                              u16* __restrict__ wp,
                                              u16* __restrict__ ap) {
  int idx = blockIdx.x * 256 + threadIdx.x;
  if (idx < O_ * KK) {
    int o = idx / KK;
    int k = idx - o * KK;
    float v;
    if (k < C_) {
      v = Wb[o * C_ + k];
    } else {
      int j = k - C_;
      v = Bs[((j >> 4) * O_ + o) * R_ + (j & 15)];
    }
    wp[idx] = f2bf(v);
  } else {
    int a = idx - O_ * KK;  // 131,072 elements of As
    ap[a] = f2bf(As[a]);
  }
}

// ---------------- kernel 2a: streaming convert ----------------
// x fp32 (24000x1024) -> xp bf16 cols 0:1024 (row stride 1152). Pure
// memory-roofline: 98 MB read + 47 MB write, no barriers, no LDS.
__global__ __launch_bounds__(256) void cvt(const float* __restrict__ x,
                                           u16* __restrict__ xp) {
  const int t0 = blockIdx.x * 256 + threadIdx.x;  // 0..511999
#pragma unroll
  for (int u = 0; u < 6; ++u) {
    const int chunk = u * 512000 + t0;            // 0..3,071,999
    const int row = chunk >> 7;                   // 0..23999
    const int cc = (chunk & 127) * 8;             // 0..1016
    const float4 v0 = *(const float4*)&x[(size_t)row * C_ + cc];
    const float4 v1 = *(const float4*)&x[(size_t)row * C_ + cc + 4];
    u16x8 o;
    o[0] = f2bf(v0.x); o[1] = f2bf(v0.y); o[2] = f2bf(v0.z); o[3] = f2bf(v0.w);
    o[4] = f2bf(v1.x); o[5] = f2bf(v1.y); o[6] = f2bf(v1.z); o[7] = f2bf(v1.w);
    *(u16x8*)&xp[(size_t)row * KK + cc] = o;
  }
}

// ---------------- kernel 2b: LoRA h-GEMM + gate ----------------
// hg[row, e*16+r] = SCALING * w[b,e] * (x_bf16 @ As^T)  -> xp cols 1024:1152.
// M=24000 (375 x 64-row tiles), N=128, K=1024, BK=64, XOR-8 conflict-free.
__global__ __launch_bounds__(256) void h_gemm(const u16* __restrict__ xp,
                                              const u16* __restrict__ ab,
                                              const float* __restrict__ w,
                                              u16* __restrict__ xpo) {
  const int mt = blockIdx.x;  // 0..374 (exact: 375*64 = 24000)
  const int tid = threadIdx.x, lane = tid & 63, wv = tid >> 6;
  const int wrow = wv & 1, wcol = wv >> 1, l15 = lane & 15, quad = lane >> 4;
  const int s7 = l15 & 7;

  __shared__ u16 lA[64 * 64];    // 8 KB
  __shared__ u16 lB[128 * 64];   // 16 KB

  const u16* gA = xp + (size_t)mt * 64 * KK;

  f32x4 acc[2][4];
#pragma unroll
  for (int i = 0; i < 2; ++i)
#pragma unroll
    for (int j = 0; j < 4; ++j) acc[i][j] = (f32x4){0.f, 0.f, 0.f, 0.f};

  int arow[2], ako[2], brow[4], bko[4];
#pragma unroll
  for (int c = 0; c < 2; ++c) {
    int idx = c * 256 + tid;            // 0..511: row=idx>>3 (0..63)
    arow[c] = idx >> 3;
    ako[c] = (((idx & 7) ^ (arow[c] & 7)) << 3);
  }
#pragma unroll
  for (int c = 0; c < 4; ++c) {
    int idx = c * 256 + tid;            // 0..1023: row=idx>>3 (0..127)
    brow[c] = idx >> 3;
    bko[c] = (((idx & 7) ^ (brow[c] & 7)) << 3);
  }

  for (int kt = 0; kt < C_ / 64; ++kt) {  // 16 iterations
    const int k0 = kt * 64;
#pragma unroll
    for (int c = 0; c < 2; ++c)
      GLL(gA + (size_t)arow[c] * KK + k0 + ako[c], &lA[(c * 256 + tid) * 8]);
#pragma unroll
    for (int c = 0; c < 4; ++c)
      GLL(ab + brow[c] * C_ + k0 + bko[c], &lB[(c * 256 + tid) * 8]);
    __syncthreads();
#pragma unroll
    for (int kk = 0; kk < 2; ++kk) {
      const int ko = (((kk * 4 + quad) ^ s7) << 3);
      bf16x8 af[2], bfr[4];
#pragma unroll
      for (int i = 0; i < 2; ++i)
        af[i] = *(const bf16x8*)&lA[(wrow * 32 + i * 16 + l15) * 64 + ko];
#pragma unroll
      for (int j = 0; j < 4; ++j)
        bfr[j] = *(const bf16x8*)&lB[(wcol * 64 + j * 16 + l15) * 64 + ko];
#pragma unroll
      for (int i = 0; i < 2; ++i)
#pragma unroll
        for (int j = 0; j < 4; ++j)
          acc[i][j] = __builtin_amdgcn_mfma_f32_16x16x32_bf16(af[i], bfr[j], acc[i][j], 0, 0, 0);
    }
    __syncthreads();
  }

  // epilogue: col -> expert e = wcol*4+j (lane-uniform), rank r = l15
#pragma unroll
  for (int j = 0; j < 4; ++j) {
    const int col = wcol * 64 + j * 16 + l15;
    const int e = wcol * 4 + j;
#pragma unroll
    for (int i = 0; i < 2; ++i) {
#pragma unroll
      for (int rr = 0; rr < 4; ++rr) {
        const int row = mt * 64 + wrow * 32 + i * 16 + quad * 4 + rr;
        const int b = row / T_;
        xpo[(size_t)row * KK + C_ + col] = f2bf(acc[i][j][rr] * (SCALING * w[b * E_ + e]));
      }
    }
  }
}

// ---------------- kernel 3: main GEMM (counted-vmcnt double buffer) ----------------
// out[row][o] = X'[row,:] . W'[o,:] + b_base[o];  M=24000 K=1152 N=1024.
// BM=BN=128, BK=64; 256 thr = 4 waves (2x2), wave out 64x64 (acc[4][4]).
// LDS 2x(16+16) KB = 64 KB -> 2 blocks/CU. Pipeline (per K-tile t, buf=t&1):
//   vmcnt(8)   : K-tile t's 8 GLLs landed; t+1's 8 still flying
//   barrier    : all waves passed their own vmcnt -> tile t visible
//   16x ds_read_b128 frags (XOR-8, conflict-free)
//   lgkmcnt(0); barrier : all waves done reading buf -> overwrite safe
//   stage K-tile t+2 into buf (8 GLL, fly under MFMA + next tile's compute)
//   setprio(1); 32 MFMA; setprio(0)
// Never vmcnt(0) until the last K-tile. mt=187 staging over-reads 64 rows past
// X' (lands in allocated W'/As region); stores row-masked.
// XCD-chunked map (1504 % 8 == 0, bijective): xcd=id&7 gets 188 consecutive
// tiles -> A-panel reuse in XCD L2; W' (2.3 MB) L2-resident.
__global__ __launch_bounds__(256, 2) void main_gemm(const u16* __restrict__ xp,
                                                    const u16* __restrict__ wp,
                                                    const float* __restrict__ bb,
                                                    float* __restrict__ out) {
  const int id = blockIdx.x;                 // 0..1503
  const int g = (id & 7) * 188 + (id >> 3);  // XCD-chunked tile index
  const int mt = g >> 3;                     // 0..187
  const int nt = g & 7;                      // 0..7
  const int tid = threadIdx.x, lane = tid & 63, wv = tid >> 6;
  const int wm = wv >> 1, wn = wv & 1, l15 = lane & 15, quad = lane >> 4;
  const int s7 = l15 & 7;

  __shared__ u16 lA[2][128 * 64];  // 2 x 16 KB
  __shared__ u16 lB[2][128 * 64];  // 2 x 16 KB

  const u16* gA = xp + (size_t)mt * 128 * KK;
  const u16* gB = wp + (size_t)nt * 128 * KK;

  f32x4 acc[4][4];
#pragma unroll
  for (int i = 0; i < 4; ++i)
#pragma unroll
    for (int j = 0; j < 4; ++j) acc[i][j] = (f32x4){0.f, 0.f, 0.f, 0.f};

  // staging: 4 GLL rounds per matrix per K-tile; idx=c*256+tid (0..1023):
  // row=idx>>3 (0..127), phys chunk p=idx&7 holds logical chunk p^(row&7).
  const u16* pA[4];
  const u16* pB[4];
  int dst[4];
#pragma unroll
  for (int c = 0; c < 4; ++c) {
    int idx = c * 256 + tid;
    int row = idx >> 3;
    int ko = (((idx & 7) ^ (row & 7)) << 3);
    pA[c] = gA + (size_t)row * KK + ko;
    pB[c] = gB + (size_t)row * KK + ko;
    dst[c] = idx * 8;
  }

  // prologue: stage K0 -> buf0, K1 -> buf1  (16 GLL outstanding)
#pragma unroll
  for (int c = 0; c < 4; ++c) GLL(pA[c], &lA[0][dst[c]]);
#pragma unroll
  for (int c = 0; c < 4; ++c) GLL(pB[c], &lB[0][dst[c]]);
#pragma unroll
  for (int c = 0; c < 4; ++c) GLL(pA[c] + 64, &lA[1][dst[c]]);
#pragma unroll
  for (int c = 0; c < 4; ++c) GLL(pB[c] + 64, &lB[1][dst[c]]);

#pragma unroll 2
  for (int t = 0; t < NKT; ++t) {
    const int cur = t & 1;
    if (t < NKT - 1) {
      asm volatile("s_waitcnt vmcnt(8)" ::: "memory");   // tile t landed; t+1 flying
    } else {
      asm volatile("s_waitcnt vmcnt(0)" ::: "memory");   // tail drain
    }
    __builtin_amdgcn_sched_barrier(0);
    __builtin_amdgcn_s_barrier();            // tile t visible to all waves
    __builtin_amdgcn_sched_barrier(0);

    bf16x8 af[4][2], bfr[4][2];
#pragma unroll
    for (int ks = 0; ks < 2; ++ks) {
      const int ko = (((ks * 4 + quad) ^ s7) << 3);
#pragma unroll
      for (int i = 0; i < 4; ++i) {
        af[i][ks] = *(const bf16x8*)&lA[cur][(wm * 64 + i * 16 + l15) * 64 + ko];
        bfr[i][ks] = *(const bf16x8*)&lB[cur][(wn * 64 + i * 16 + l15) * 64 + ko];
      }
    }
    asm volatile("s_waitcnt lgkmcnt(0)" ::: "memory");
    __builtin_amdgcn_sched_barrier(0);
    __builtin_amdgcn_s_barrier();            // all waves done reading buf[cur]
    __builtin_amdgcn_sched_barrier(0);

    if (t + 2 < NKT) {                       // stage K-tile t+2 into buf[cur]
      const int k2 = (t + 2) * 64;
#pragma unroll
      for (int c = 0; c < 4; ++c) GLL(pA[c] + k2, &lA[cur][dst[c]]);
#pragma unroll
      for (int c = 0; c < 4; ++c) GLL(pB[c] + k2, &lB[cur][dst[c]]);
    }

    __builtin_amdgcn_s_setprio(1);
#pragma unroll
    for (int ks = 0; ks < 2; ++ks)
#pragma unroll
      for (int i = 0; i < 4; ++i)
#pragma unroll
        for (int j = 0; j < 4; ++j)
          acc[i][j] = __builtin_amdgcn_mfma_f32_16x16x32_bf16(af[i][ks], bfr[j][ks],
                                                              acc[i][j], 0, 0, 0);
    __builtin_amdgcn_s_setprio(0);
  }

#pragma unroll
  for (int j = 0; j < 4; ++j) {
    const int col = nt * 128 + wn * 64 + j * 16 + l15;
    const float bias = bb[col];
#pragma unroll
    for (int i = 0; i < 4; ++i) {
#pragma unroll
      for (int rr = 0; rr < 4; ++rr) {
        const int row = mt * 128 + wm * 64 + i * 16 + quad * 4 + rr;
        if (row < BT) out[(size_t)row * O_ + col] = acc[i][j][rr] + bias;
      }
    }
  }
}

extern "C" void kernel_launch(void* const* d_in, const int* in_sizes, int n_in,
                              void* d_out, int out_size, void* d_ws, size_t ws_size,
                              hipStream_t stream) {
  const float* x = (const float*)d_in[0];    // (16,1500,1024)
  const float* w = (const float*)d_in[1];    // (16,8)
  const float* Wb = (const float*)d_in[2];   // (1024,1024)
  const float* bb = (const float*)d_in[3];   // (1024,)
  const float* As = (const float*)d_in[4];   // (8,16,1024)
  const float* Bs = (const float*)d_in[5];   // (8,1024,16)
  float* out = (float*)d_out;                // (16,1500,1024) fp32

  // ws: X' (24000x1152 u16, 55.30 MB) | W' (1024x1152 u16, 2.36 MB) | Asb (128x1024 u16, 0.26 MB)
  // main_gemm mt=187 staging over-reads rows 24000..24063 -> land in W' region (allocated, masked).
  u16* xp = (u16*)d_ws;
  u16* wp = xp + (size_t)BT * KK;
  u16* ap = wp + (size_t)O_ * KK;

  prep_w<<<(O_ * KK + ER * C_) / 256, 256, 0, stream>>>(Wb, Bs, As, wp, ap);
  cvt<<<2000, 256, 0, stream>>>(x, xp);
  h_gemm<<<375, 256, 0, stream>>>(xp, ap, w, xp);
  main_gemm<<<1504, 256, 0, stream>>>(xp, wp, bb, out);
}